// Round 8
// baseline (280.605 us; speedup 1.0000x reference)
//
#include <hip/hip_runtime.h>
#include <hip/hip_bf16.h>
#include <math.h>

#define DIMC 1024
#define HEADS 16
#define HD 64
#define HIDDEN 4096
#define BATCH 2
#define SEQ 2048
#define TOK (BATCH*SEQ)

typedef unsigned short u16;
typedef __attribute__((ext_vector_type(8))) short short8;
typedef __attribute__((ext_vector_type(4))) float f32x4;

__device__ __forceinline__ u16 f2bf(float f) {
  unsigned u = __float_as_uint(f);
  u += 0x7fff + ((u >> 16) & 1);
  return (u16)(u >> 16);
}
__device__ __forceinline__ float bf2f(u16 h) {
  return __uint_as_float(((unsigned)h) << 16);
}

__device__ __forceinline__ void gl_lds16(const void* g, void* l) {
  __builtin_amdgcn_global_load_lds(
      (__attribute__((address_space(1))) void*)g,
      (__attribute__((address_space(3))) void*)l, 16, 0, 0);
}

// read a 16B chunk from a 128B-row LDS tile with per-row XOR swizzle
__device__ __forceinline__ const short8* lds_row128(const u16* base, int row, int chunk) {
  return (const short8*)((const char*)base + row * 128 + (((chunk) ^ (row & 7)) << 4));
}

// ---------------- LayerNorm (fp32 in -> bf16 out), one block per row ----------------
__global__ __launch_bounds__(256) void ln_kernel(
    const float* __restrict__ x, const float* __restrict__ w,
    const float* __restrict__ b, u16* __restrict__ out)
{
  int row = blockIdx.x, tid = threadIdx.x;
  const float4* xr = (const float4*)(x + (size_t)row * DIMC);
  float4 v = xr[tid];
  float s = v.x + v.y + v.z + v.w;
  float s2 = v.x*v.x + v.y*v.y + v.z*v.z + v.w*v.w;
  for (int off = 32; off > 0; off >>= 1) {
    s  += __shfl_down(s, off);
    s2 += __shfl_down(s2, off);
  }
  __shared__ float red[8];
  int lane = tid & 63, wv = tid >> 6;
  if (lane == 0) { red[wv] = s; red[4 + wv] = s2; }
  __syncthreads();
  float S  = red[0] + red[1] + red[2] + red[3];
  float S2 = red[4] + red[5] + red[6] + red[7];
  float mean = S * (1.f / DIMC);
  float var  = S2 * (1.f / DIMC) - mean * mean;
  float inv  = rsqrtf(var + 1e-5f);
  int base = tid * 4;
  float vv[4] = {v.x, v.y, v.z, v.w};
#pragma unroll
  for (int j = 0; j < 4; ++j)
    out[(size_t)row * DIMC + base + j] = f2bf((vv[j] - mean) * inv * w[base + j] + b[base + j]);
}

// ---------------- transpose + cast fp32 [K][N] -> bf16 [N][K] ----------------
__global__ __launch_bounds__(256) void transpose_cast(
    const float* __restrict__ W, u16* __restrict__ Wt, int K, int N)
{
  __shared__ float t[32][33];
  int n0 = blockIdx.x * 32, k0 = blockIdx.y * 32;
  for (int r = threadIdx.y; r < 32; r += 8)
    t[r][threadIdx.x] = W[(size_t)(k0 + r) * N + n0 + threadIdx.x];
  __syncthreads();
  for (int r = threadIdx.y; r < 32; r += 8)
    Wt[(size_t)(n0 + r) * K + k0 + threadIdx.x] = f2bf(t[threadIdx.x][r]);
}

// ================= gemm256: 256x256 tile, BK=64, 8 waves, T3 minimum-2-phase =================
// C[M][N] = A[M][K]*Bt[N][K]^T + bias (EPI0) / +bias,gelu (EPI1), bf16 out.
// Per tile: STAGE(next tile into other buf) FIRST, then ds_read+MFMA on current,
// then ONE __syncthreads (its vmcnt(0) drain is covered by the whole tile's
// compute). AI = 128 FLOP/staged-byte (2x the 128-square tile) -> lifts the
// per-CU staging-request-rate ceiling from ~860 to ~1700 TF.
// LDS XOR swizzle (phys chunk = logical ^ (row&7)): inverse on global source
// (linear gl_lds dest), forward on fragment reads. Verified in round 6.
template<int EPI>
__global__ __launch_bounds__(512, 2) void gemm256(
    const u16* __restrict__ A, const u16* __restrict__ Bt,
    const float* __restrict__ bias, u16* __restrict__ outb,
    int M, int N, int K)
{
  __shared__ u16 AB[2][2][256 * 64];   // [buf][A/B][row*64+col] = 128 KB
  int tid = threadIdx.x;
  int lane = tid & 63, wid = tid >> 6;
  int wr = wid >> 2, wn = wid & 3;          // wave -> (M-half, N-quarter)
  int rofs = lane & 15, q4 = lane >> 4;

  // --- XCD-chunked + 4x4 L2-blocked grid swizzle (bijective; nwg%8==0, gx%4==0) ---
  int nwg = gridDim.x * gridDim.y;
  int orig = blockIdx.y * gridDim.x + blockIdx.x;
  int wg = (orig & 7) * (nwg >> 3) + (orig >> 3);
  int gi = wg >> 4, wi = wg & 15;
  int gx4 = gridDim.x >> 2;
  int bx = (gi % gx4) * 4 + (wi & 3);
  int by = (gi / gx4) * 4 + (wi >> 2);
  int m0 = by * 256, n0 = bx * 256;
  int mb = wr * 128, nb = wn * 64;

  f32x4 acc[8][4] = {};

  // staging: linear LDS pos p = tid + j*512 (16B units); row = p>>3,
  // phys chunk = p&7, source logical chunk = (p&7)^(row&7).
  int off[4];
#pragma unroll
  for (int j = 0; j < 4; ++j) {
    int p = tid + j * 512;
    int row = p >> 3;
    int cl = (p & 7) ^ (row & 7);
    off[j] = row * K + cl * 8;
  }
  const u16* gA = A  + (size_t)m0 * K;
  const u16* gB = Bt + (size_t)n0 * K;

  auto stage = [&](int b, int t) {
#pragma unroll
    for (int j = 0; j < 4; ++j) {
      int p8 = (tid + j * 512) * 8;
      gl_lds16(gA + off[j] + t * 64, &AB[b][0][p8]);
      gl_lds16(gB + off[j] + t * 64, &AB[b][1][p8]);
    }
  };
  auto comp = [&](int b) {
    const char* Ab = (const char*)&AB[b][0][0];
    const char* Bb = (const char*)&AB[b][1][0];
    short8 bf[4][2];
#pragma unroll
    for (int nn = 0; nn < 4; ++nn)
#pragma unroll
      for (int kk = 0; kk < 2; ++kk) {
        int row = nb + nn * 16 + rofs;
        bf[nn][kk] = *(const short8*)(Bb + row * 128 + ((((kk << 2) | q4) ^ (row & 7)) << 4));
      }
#pragma unroll
    for (int mg = 0; mg < 2; ++mg) {
      short8 af[4][2];
#pragma unroll
      for (int mm = 0; mm < 4; ++mm)
#pragma unroll
        for (int kk = 0; kk < 2; ++kk) {
          int row = mb + (mg * 4 + mm) * 16 + rofs;
          af[mm][kk] = *(const short8*)(Ab + row * 128 + ((((kk << 2) | q4) ^ (row & 7)) << 4));
        }
      __builtin_amdgcn_s_setprio(1);
#pragma unroll
      for (int kk = 0; kk < 2; ++kk)
#pragma unroll
        for (int mm = 0; mm < 4; ++mm)
#pragma unroll
          for (int nn = 0; nn < 4; ++nn)
            acc[mg * 4 + mm][nn] = __builtin_amdgcn_mfma_f32_16x16x32_bf16(
                af[mm][kk], bf[nn][kk], acc[mg * 4 + mm][nn], 0, 0, 0);
      __builtin_amdgcn_s_setprio(0);
    }
  };

  int NT = K >> 6;
  stage(0, 0);
  __syncthreads();                 // drain prologue stage
  int cur = 0;
  for (int t = 0; t < NT; ++t) {
    if (t + 1 < NT) stage(cur ^ 1, t + 1);   // issue next-tile loads FIRST
    comp(cur);                                // compute covers the stage
    __syncthreads();                          // vmcnt(0)+lgkmcnt(0)+barrier
    cur ^= 1;
  }

  // ---- coalesced epilogue via LDS bounce (AB reused as [256][256] bf16) ----
  u16* Ct = &AB[0][0][0];
#pragma unroll
  for (int nn = 0; nn < 4; ++nn) {
    int ccol = nb + nn * 16 + rofs;
    float bv = bias[n0 + ccol];
#pragma unroll
    for (int m = 0; m < 8; ++m)
#pragma unroll
      for (int r = 0; r < 4; ++r) {
        int row = mb + m * 16 + q4 * 4 + r;
        float v = acc[m][nn][r] + bv;
        if (EPI == 1) v = 0.5f * v * (1.f + erff(v * 0.70710678118f));
        Ct[row * 256 + ccol] = f2bf(v);
      }
  }
  __syncthreads();
  for (int c = tid; c < 256 * 32; c += 512) {   // 256 rows x 32 chunks of 16B
    int row = c >> 5, offb = (c & 31) * 8;
    *(short8*)(outb + (size_t)(m0 + row) * N + n0 + offb) = *(const short8*)&Ct[row * 256 + offb];
  }
}

// ---------------- bf16 GEMM BMx128 (for N=1024 shapes), 2-phase dbuf ----------------
// EPI: 2 = +bias + res -> fp32
template<int EPI, int BM>
__global__ __launch_bounds__(256) void gemm_bt(
    const u16* __restrict__ A, const u16* __restrict__ Bt,
    const float* __restrict__ bias, const float* __restrict__ res,
    u16* __restrict__ outb, float* __restrict__ outf,
    int M, int N, int K)
{
  constexpr int AMM = BM / 32;
  constexpr int HALF = BM / 2;
  __shared__ u16 shm[(BM + 128) * 32 * 2];
  u16* As[2] = { shm,             shm + BM * 32 };
  u16* Bs[2] = { shm + 2 * BM * 32, shm + 2 * BM * 32 + 128 * 32 };
  int tid = threadIdx.x;
  int lane = tid & 63, w = tid >> 6;
  int wr = w >> 1, wc = w & 1;

  int nwg = gridDim.x * gridDim.y;
  int orig = blockIdx.y * gridDim.x + blockIdx.x;
  int wg = (orig & 7) * (nwg >> 3) + (orig >> 3);
  int gi = wg >> 4, wi = wg & 15;
  int gx4 = gridDim.x >> 2;
  int bx = (gi % gx4) * 4 + (wi & 3);
  int by = (gi / gx4) * 4 + (wi >> 2);
  int m0 = by * BM, n0 = bx * 128;

  f32x4 acc[AMM][4] = {};

  int trow = tid >> 2;
  int tk = (((tid & 3) ^ ((tid >> 3) & 3)) * 8);
  const u16* ga = A  + (size_t)(m0 + trow) * K + tk;
  const u16* gb = Bt + (size_t)(n0 + trow) * K + tk;
  int rofs = lane & 15, q4 = lane >> 4;
  int ach = ((q4 ^ ((rofs >> 1) & 3)) << 4);
  int nt = K >> 5;

  auto stage = [&](int buf) {
    gl_lds16(ga, As[buf] + tid * 8);
    if (BM == 128) gl_lds16(ga + (size_t)64 * K, As[buf] + tid * 8 + 2048);
    gl_lds16(gb, Bs[buf] + tid * 8);
    gl_lds16(gb + (size_t)64 * K, Bs[buf] + tid * 8 + 2048);
    ga += 32; gb += 32;
  };
  auto compute = [&](int buf) {
    short8 af[AMM], bfr[4];
#pragma unroll
    for (int mm = 0; mm < AMM; ++mm)
      af[mm] = *(const short8*)((const char*)As[buf] + (wr * HALF + mm * 16 + rofs) * 64 + ach);
#pragma unroll
    for (int nn = 0; nn < 4; ++nn)
      bfr[nn] = *(const short8*)((const char*)Bs[buf] + (wc * 64 + nn * 16 + rofs) * 64 + ach);
#pragma unroll
    for (int mm = 0; mm < AMM; ++mm)
#pragma unroll
      for (int nn = 0; nn < 4; ++nn)
        acc[mm][nn] = __builtin_amdgcn_mfma_f32_16x16x32_bf16(af[mm], bfr[nn], acc[mm][nn], 0, 0, 0);
  };

  stage(0);
  __syncthreads();
  for (int t = 0; t < nt; t += 2) {
    if (t + 1 < nt) stage(1);
    compute(0);
    __syncthreads();
    if (t + 2 < nt) stage(0);
    compute(1);
    __syncthreads();
  }

  if (EPI == 0 || EPI == 1) {
    u16* C = shm;
#pragma unroll
    for (int nn = 0; nn < 4; ++nn) {
      int ccol = wc * 64 + nn * 16 + rofs;
      float bv = bias[n0 + ccol];
#pragma unroll
      for (int mm = 0; mm < AMM; ++mm)
#pragma unroll
        for (int r = 0; r < 4; ++r) {
          int crow = wr * HALF + mm * 16 + q4 * 4 + r;
          float v = acc[mm][nn][r] + bv;
          if (EPI == 1) v = 0.5f * v * (1.f + erff(v * 0.70710678118f));
          C[crow * 128 + ccol] = f2bf(v);
        }
    }
    __syncthreads();
    for (int c = tid; c < BM * 16; c += 256) {
      int row = c >> 4, off = (c & 15) * 8;
      *(short8*)(outb + (size_t)(m0 + row) * N + n0 + off) = *(const short8*)&C[row * 128 + off];
    }
  } else {
    float* Cf = (float*)shm;
#pragma unroll
    for (int p = 0; p < 2; ++p) {
      if (wr == p) {
#pragma unroll
        for (int nn = 0; nn < 4; ++nn) {
          int ccol = wc * 64 + nn * 16 + rofs;
          float bv = bias[n0 + ccol];
#pragma unroll
          for (int mm = 0; mm < AMM; ++mm)
#pragma unroll
            for (int r = 0; r < 4; ++r)
              Cf[(mm * 16 + q4 * 4 + r) * 128 + ccol] = acc[mm][nn][r] + bv;
        }
      }
      __syncthreads();
      for (int c = tid; c < HALF * 32; c += 256) {
        int row = c >> 5, off = (c & 31) * 4;
        size_t idx = (size_t)(m0 + p * HALF + row) * N + n0 + off;
        float4 rv = *(const float4*)(res + idx);
        float4 cv = *(const float4*)&Cf[row * 128 + off];
        cv.x += rv.x; cv.y += rv.y; cv.z += rv.z; cv.w += rv.w;
        *(float4*)(outf + idx) = cv;
      }
      __syncthreads();
    }
  }
}

// ---------------- RoPE + QKV split (+V transpose) ----------------
// Q is pre-scaled by 0.125 * log2(e) so attention scores land in log2 domain.
__global__ __launch_bounds__(256) void rope_split(
    const u16* __restrict__ qkv, const int* __restrict__ pos,
    u16* __restrict__ Q, u16* __restrict__ Kk, u16* __restrict__ Vt)
{
  int st = blockIdx.x, bh = blockIdx.y;
  int b = bh >> 4, hh = bh & 15;
  int s0 = st * 64;
  int tid = threadIdx.x;
  __shared__ u16 vtile[64][72];

  for (int i = tid; i < 64 * 32; i += 256) {
    int sl = i >> 5, dp = i & 31;
    int s = s0 + sl;
    float p = (float)pos[b * SEQ + s];
    float freq = exp2f((float)dp * -0.4152410118609203f); // 10000^(-dp/32)
    float ang = p * freq;
    float sn, c;
    __sincosf(ang, &sn, &c);
    const u16* qr = qkv + (size_t)(b * SEQ + s) * 3072 + hh * 64;
    float q1 = bf2f(qr[dp]),        q2 = bf2f(qr[dp + 32]);
    float k1 = bf2f(qr[1024 + dp]), k2 = bf2f(qr[1024 + dp + 32]);
    size_t ob = ((size_t)bh * SEQ + s) * HD;
    const float QS = 0.18033688011112042f; // 0.125 * log2(e)
    Q[ob + dp]       = f2bf((q1 * c - q2 * sn) * QS);
    Q[ob + dp + 32]  = f2bf((q2 * c + q1 * sn) * QS);
    Kk[ob + dp]      = f2bf(k1 * c - k2 * sn);
    Kk[ob + dp + 32] = f2bf(k2 * c + k1 * sn);
  }
  for (int i = tid; i < 64 * 64; i += 256) {
    int sl = i >> 6, d = i & 63;
    vtile[d][sl] = qkv[(size_t)(b * SEQ + s0 + sl) * 3072 + 2048 + hh * 64 + d];
  }
  __syncthreads();
  for (int i = tid; i < 64 * 64; i += 256) {
    int d = i >> 6, sl = i & 63;
    Vt[((size_t)bh * HD + d) * SEQ + s0 + sl] = vtile[d][sl];
  }
}

// ---------------- flash attention: 64 q-rows/block, KV tiles of 64, 2-phase dbuf ----------------
// No-max softmax (bounded-score argument); row-sum via ones-MFMA;
// coalesced O-write via LDS bounce.
__global__ __launch_bounds__(256) void attn_kernel(
    const u16* __restrict__ Q, const u16* __restrict__ K,
    const u16* __restrict__ Vt, u16* __restrict__ O)
{
  __shared__ u16 Ks[2][64 * 64];
  __shared__ u16 Vs[2][64 * 64];
  __shared__ u16 Ps[4 * 16 * 64];
  int qt = blockIdx.x, bh = blockIdx.y;
  int b = bh >> 4, hh = bh & 15;
  const u16* Qp = Q + ((size_t)bh * SEQ + qt * 64) * HD;
  const u16* Kp = K + (size_t)bh * SEQ * HD;
  const u16* Vp = Vt + (size_t)bh * HD * SEQ;
  int tid = threadIdx.x, lane = tid & 63, w = tid >> 6;
  int rofs = lane & 15, q4 = lane >> 4;
  int kofs = q4 * 8;

  short8 aq0 = *(const short8*)&Qp[(w * 16 + rofs) * HD + kofs];
  short8 aq1 = *(const short8*)&Qp[(w * 16 + rofs) * HD + 32 + kofs];

  short8 ones;
#pragma unroll
  for (int j = 0; j < 8; ++j) ones[j] = (short)0x3F80; // bf16 1.0

  f32x4 o[4] = {};
  f32x4 lsum = {};

  int srow = tid >> 3;
  int sg0 = ((tid & 7) ^ (srow & 7)) * 8; // swizzled source chunk (elements)
  u16* pw = &Ps[w * 16 * 64];

#define A_STAGE(BUF, T0) do { \
    gl_lds16(Kp + (size_t)((T0) + srow) * HD + sg0, &Ks[BUF][tid * 8]); \
    gl_lds16(Kp + (size_t)((T0) + 32 + srow) * HD + sg0, &Ks[BUF][tid * 8 + 2048]); \
    gl_lds16(Vp + (size_t)srow * SEQ + (T0) + sg0, &Vs[BUF][tid * 8]); \
    gl_lds16(Vp + (size_t)(32 + srow) * SEQ + (T0) + sg0, &Vs[BUF][tid * 8 + 2048]); \
  } while (0)

  auto tile = [&](const u16* KsB, const u16* VsB) {
    f32x4 s[4] = {};
#pragma unroll
    for (int n = 0; n < 4; ++n) {
      int krow = n * 16 + rofs;
      short8 bk0 = *lds_row128(KsB, krow, q4);
      short8 bk1 = *lds_row128(KsB, krow, 4 + q4);
      s[n] = __builtin_amdgcn_mfma_f32_16x16x32_bf16(aq0, bk0, s[n], 0, 0, 0);
      s[n] = __builtin_amdgcn_mfma_f32_16x16x32_bf16(aq1, bk1, s[n], 0, 0, 0);
    }
#pragma unroll
    for (int n = 0; n < 4; ++n)
#pragma unroll
      for (int r = 0; r < 4; ++r) {
        int prow = q4 * 4 + r;
        int pbyte = (n * 16 + rofs) * 2;
        float p = __builtin_amdgcn_exp2f(s[n][r]);
        *(u16*)((char*)pw + prow * 128 + (pbyte ^ ((prow & 7) << 4))) = f2bf(p);
      }
    short8 pa0 = *lds_row128(pw, rofs, q4);
    short8 pa1 = *lds_row128(pw, rofs, 4 + q4);
    lsum = __builtin_amdgcn_mfma_f32_16x16x32_bf16(pa0, ones, lsum, 0, 0, 0);
    lsum = __builtin_amdgcn_mfma_f32_16x16x32_bf16(pa1, ones, lsum, 0, 0, 0);
#pragma unroll
    for (int n = 0; n < 4; ++n) {
      int vrow = n * 16 + rofs;
      short8 bv0 = *lds_row128(VsB, vrow, q4);
      short8 bv1 = *lds_row128(VsB, vrow, 4 + q4);
      o[n] = __builtin_amdgcn_mfma_f32_16x16x32_bf16(pa0, bv0, o[n], 0, 0, 0);
      o[n] = __builtin_amdgcn_mfma_f32_16x16x32_bf16(pa1, bv1, o[n], 0, 0, 0);
    }
  };

  A_STAGE(0, 0);
  __syncthreads();
  for (int t0 = 0; t0 < SEQ; t0 += 128) {
    if (t0 + 64 < SEQ) A_STAGE(1, t0 + 64);
    tile(Ks[0], Vs[0]);
    __syncthreads();
    if (t0 + 128 < SEQ) A_STAGE(0, t0 + 128);
    tile(Ks[1], Vs[1]);
    __syncthreads();
  }
#undef A_STAGE

#pragma unroll
  for (int r = 0; r < 4; ++r) {
    float inv = 1.f / lsum[r];
    int lrow = w * 16 + q4 * 4 + r;
#pragma unroll
    for (int n = 0; n < 4; ++n)
      Ps[lrow * 64 + n * 16 + rofs] = f2bf(o[n][r] * inv);
  }
  __syncthreads();
  for (int c = tid; c < 512; c += 256) {     // 64 rows x 8 chunks of 16B
    int row = c >> 3, off = (c & 7) * 8;
    int sq = qt * 64 + row;
    *(short8*)(O + ((size_t)b * SEQ + sq) * DIMC + hh * 64 + off) = *(const short8*)&Ps[row * 64 + off];
  }
}

extern "C" void kernel_launch(void* const* d_in, const int* in_sizes, int n_in,
                              void* d_out, int out_size, void* d_ws, size_t ws_size,
                              hipStream_t stream) {
  const float* x     = (const float*)d_in[0];
  const int*   pos   = (const int*)  d_in[1];
  const float* ln1_w = (const float*)d_in[2];
  const float* ln1_b = (const float*)d_in[3];
  const float* qkv_w = (const float*)d_in[4];
  const float* qkv_b = (const float*)d_in[5];
  const float* o_w   = (const float*)d_in[6];
  const float* o_b   = (const float*)d_in[7];
  const float* ln2_w = (const float*)d_in[8];
  const float* ln2_b = (const float*)d_in[9];
  const float* w1    = (const float*)d_in[10];
  const float* b1    = (const float*)d_in[11];
  const float* w2    = (const float*)d_in[12];
  const float* b2    = (const float*)d_in[13];
  float* out = (float*)d_out;

  // workspace layout (bytes) — total 92,274,688 (88 MB), carefully aliased
  char* ws = (char*)d_ws;
  u16* WqkvT = (u16*)(ws + 0);          // 3072x1024 bf16 (6 MB)
  u16* WoT   = (u16*)(ws + 6291456);    // 1024x1024 (2 MB)
  u16* W1T   = (u16*)(ws + 8388608);    // 4096x1024 (8 MB)
  u16* W2T   = (u16*)(ws + 16777216);   // 1024x4096 (8 MB)
  u16* xn    = (u16*)(ws + 25165824);   // 4096x1024 (8 MB)
  u16* qkvbf = (u16*)(ws + 33554432);   // 4096x3072 (24 MB)
  u16* Qb    = (u16*)(ws + 58720256);   // 8 MB
  u16* Kb    = (u16*)(ws + 67108864);   // 8 MB
  u16* Vtb   = (u16*)(ws + 75497472);   // 8 MB
  u16* attnb = (u16*)(ws + 83886080);   // 8 MB
  u16* hbuf  = (u16*)(ws + 25165824);   // 4096x4096 (32 MB) — aliases xn+qkvbf (dead)
  float* x2  = (float*)(ws + 58720256); // 16 MB — aliases Qb+Kb (dead after attn)
  u16* xn2   = (u16*)(ws + 75497472);   // 8 MB — aliases Vtb (dead after attn)

  transpose_cast<<<dim3(3072/32, 1024/32), dim3(32, 8), 0, stream>>>(qkv_w, WqkvT, 1024, 3072);
  transpose_cast<<<dim3(1024/32, 1024/32), dim3(32, 8), 0, stream>>>(o_w,  WoT,  1024, 1024);
  transpose_cast<<<dim3(4096/32, 1024/32), dim3(32, 8), 0, stream>>>(w1,   W1T,  1024, 4096);
  transpose_cast<<<dim3(1024/32, 4096/32), dim3(32, 8), 0, stream>>>(w2,   W2T,  4096, 1024);

  ln_kernel<<<TOK, 256, 0, stream>>>(x, ln1_w, ln1_b, xn);
  // 256x256 tiles for the two big GEMMs; grids: (N/256, M/256)
  gemm256<0><<<dim3(12, 16), 512, 0, stream>>>(xn, WqkvT, qkv_b, qkvbf, 4096, 3072, 1024);
  rope_split<<<dim3(32, 32), 256, 0, stream>>>(qkvbf, pos, Qb, Kb, Vtb);
  attn_kernel<<<dim3(32, 32), 256, 0, stream>>>(Qb, Kb, Vtb, attnb);
  gemm_bt<2,64><<<dim3(8, 64), 256, 0, stream>>>(attnb, WoT, o_b, x, nullptr, x2, 4096, 1024, 1024);
  ln_kernel<<<TOK, 256, 0, stream>>>(x2, ln2_w, ln2_b, xn2);
  gemm256<1><<<dim3(16, 16), 512, 0, stream>>>(xn2, W1T, b1, hbuf, 4096, 4096, 1024);
  gemm_bt<2,64><<<dim3(8, 64), 256, 0, stream>>>(hbuf, W2T, b2, x2, nullptr, out, 4096, 1024, 4096);
}

// Round 10
// 256.611 us; speedup vs baseline: 1.0935x; 1.0935x over previous
//
#include <hip/hip_runtime.h>
#include <hip/hip_bf16.h>
#include <math.h>

#define DIMC 1024
#define HEADS 16
#define HD 64
#define HIDDEN 4096
#define BATCH 2
#define SEQ 2048
#define TOK (BATCH*SEQ)

typedef unsigned short u16;
typedef __attribute__((ext_vector_type(8))) short short8;
typedef __attribute__((ext_vector_type(4))) float f32x4;

__device__ __forceinline__ u16 f2bf(float f) {
  unsigned u = __float_as_uint(f);
  u += 0x7fff + ((u >> 16) & 1);
  return (u16)(u >> 16);
}
__device__ __forceinline__ float bf2f(u16 h) {
  return __uint_as_float(((unsigned)h) << 16);
}

__device__ __forceinline__ void gl_lds16(const void* g, void* l) {
  __builtin_amdgcn_global_load_lds(
      (__attribute__((address_space(1))) void*)g,
      (__attribute__((address_space(3))) void*)l, 16, 0, 0);
}

// read a 16B chunk from a 128B-row LDS tile with per-row XOR swizzle (attn)
__device__ __forceinline__ const short8* lds_row128(const u16* base, int row, int chunk) {
  return (const short8*)((const char*)base + row * 128 + (((chunk) ^ (row & 7)) << 4));
}

// ---------------- LayerNorm (fp32 in -> bf16 out), one block per row ----------------
__global__ __launch_bounds__(256) void ln_kernel(
    const float* __restrict__ x, const float* __restrict__ w,
    const float* __restrict__ b, u16* __restrict__ out)
{
  int row = blockIdx.x, tid = threadIdx.x;
  const float4* xr = (const float4*)(x + (size_t)row * DIMC);
  float4 v = xr[tid];
  float s = v.x + v.y + v.z + v.w;
  float s2 = v.x*v.x + v.y*v.y + v.z*v.z + v.w*v.w;
  for (int off = 32; off > 0; off >>= 1) {
    s  += __shfl_down(s, off);
    s2 += __shfl_down(s2, off);
  }
  __shared__ float red[8];
  int lane = tid & 63, wv = tid >> 6;
  if (lane == 0) { red[wv] = s; red[4 + wv] = s2; }
  __syncthreads();
  float S  = red[0] + red[1] + red[2] + red[3];
  float S2 = red[4] + red[5] + red[6] + red[7];
  float mean = S * (1.f / DIMC);
  float var  = S2 * (1.f / DIMC) - mean * mean;
  float inv  = rsqrtf(var + 1e-5f);
  int base = tid * 4;
  float vv[4] = {v.x, v.y, v.z, v.w};
#pragma unroll
  for (int j = 0; j < 4; ++j)
    out[(size_t)row * DIMC + base + j] = f2bf((vv[j] - mean) * inv * w[base + j] + b[base + j]);
}

// ---------------- transpose + cast fp32 [K][N] -> bf16 [N][K] ----------------
__global__ __launch_bounds__(256) void transpose_cast(
    const float* __restrict__ W, u16* __restrict__ Wt, int K, int N)
{
  __shared__ float t[32][33];
  int n0 = blockIdx.x * 32, k0 = blockIdx.y * 32;
  for (int r = threadIdx.y; r < 32; r += 8)
    t[r][threadIdx.x] = W[(size_t)(k0 + r) * N + n0 + threadIdx.x];
  __syncthreads();
  for (int r = threadIdx.y; r < 32; r += 8)
    Wt[(size_t)(n0 + r) * K + k0 + threadIdx.x] = f2bf(t[threadIdx.x][r]);
}

// ---------------- bf16 GEMM: C[M][N] = A[M][K] * Bt[N][K]^T ----------------
// Tile BM x 128, BK=64, 2-phase double-buffer (keeps >=2 blocks/CU: 64KB LDS
// at BM=128, 48KB at BM=64 -> cross-block overlap covers drains). Halved step
// count vs BK=32 halves the per-FLOP fixed drain+barrier overhead.
// LDS rows are 128B (8 chunks of 16B); swizzle phys_chunk = logical ^ (row&7),
// inverse-applied on the global source (linear gl_lds dest), forward on reads.
// Grid placement: bijective XCD chunking + 4x4 L2 groups (nwg%8==0, gx%4==0).
// EPI: 0 = +bias -> bf16 ; 1 = +bias -> gelu -> bf16 ; 2 = +bias + res -> fp32
template<int EPI, int BM>
__global__ __launch_bounds__(256) void gemm_bt(
    const u16* __restrict__ A, const u16* __restrict__ Bt,
    const float* __restrict__ bias, const float* __restrict__ res,
    u16* __restrict__ outb, float* __restrict__ outf,
    int M, int N, int K)
{
  constexpr int AMM  = BM / 32;           // A fragments per wave (M dir)
  constexpr int HALF = BM / 2;
  constexpr int AJ   = BM / 32;           // A stage chunks per thread
  constexpr int ASZ  = BM * 64;           // elements per A buffer
  constexpr int BSZ  = 128 * 64;          // elements per B buffer
  __shared__ u16 shm[(BM + 128) * 64 * 2]; // [A0|A1|B0|B1]
  int tid = threadIdx.x;
  int lane = tid & 63, w = tid >> 6;
  int wr = w >> 1, wc = w & 1;

  // --- XCD-chunked + 4x4 L2-blocked grid swizzle (bijective) ---
  int nwg = gridDim.x * gridDim.y;
  int orig = blockIdx.y * gridDim.x + blockIdx.x;
  int wg = (orig & 7) * (nwg >> 3) + (orig >> 3);
  int gi = wg >> 4, wi = wg & 15;
  int gx4 = gridDim.x >> 2;
  int bx = (gi % gx4) * 4 + (wi & 3);
  int by = (gi / gx4) * 4 + (wi >> 2);
  int m0 = by * BM, n0 = bx * 128;

  f32x4 acc[AMM][4] = {};

  // staging addresses: linear LDS pos p = tid + j*256 (16B units);
  // row = p>>3, phys chunk = p&7, source logical chunk = (p&7)^(row&7).
  int offA[AJ], offB[4];
#pragma unroll
  for (int j = 0; j < AJ; ++j) {
    int p = tid + j * 256, row = p >> 3, cl = (p & 7) ^ (row & 7);
    offA[j] = (m0 + row) * K + cl * 8;
  }
#pragma unroll
  for (int j = 0; j < 4; ++j) {
    int p = tid + j * 256, row = p >> 3, cl = (p & 7) ^ (row & 7);
    offB[j] = (n0 + row) * K + cl * 8;
  }
  int rofs = lane & 15, q4 = lane >> 4;
  int NT = K >> 6;

  auto stage = [&](int buf, int t) {
    u16* Ab = shm + buf * ASZ;
    u16* Bb = shm + 2 * ASZ + buf * BSZ;
#pragma unroll
    for (int j = 0; j < AJ; ++j)
      gl_lds16(A + offA[j] + t * 64, Ab + (tid + j * 256) * 8);
#pragma unroll
    for (int j = 0; j < 4; ++j)
      gl_lds16(Bt + offB[j] + t * 64, Bb + (tid + j * 256) * 8);
  };
  auto compute = [&](int buf) {
    const char* Ab = (const char*)(shm + buf * ASZ);
    const char* Bb = (const char*)(shm + 2 * ASZ + buf * BSZ);
    short8 af[AMM][2], bfr[4][2];
#pragma unroll
    for (int mm = 0; mm < AMM; ++mm)
#pragma unroll
      for (int kk = 0; kk < 2; ++kk) {
        int row = wr * HALF + mm * 16 + rofs;
        af[mm][kk] = *(const short8*)(Ab + row * 128 +
                                      ((((kk << 2) | q4) ^ (row & 7)) << 4));
      }
#pragma unroll
    for (int nn = 0; nn < 4; ++nn)
#pragma unroll
      for (int kk = 0; kk < 2; ++kk) {
        int row = wc * 64 + nn * 16 + rofs;
        bfr[nn][kk] = *(const short8*)(Bb + row * 128 +
                                       ((((kk << 2) | q4) ^ (row & 7)) << 4));
      }
#pragma unroll
    for (int kk = 0; kk < 2; ++kk)
#pragma unroll
      for (int mm = 0; mm < AMM; ++mm)
#pragma unroll
        for (int nn = 0; nn < 4; ++nn)
          acc[mm][nn] = __builtin_amdgcn_mfma_f32_16x16x32_bf16(
              af[mm][kk], bfr[nn][kk], acc[mm][nn], 0, 0, 0);
  };

  stage(0, 0);
  __syncthreads();                 // drain prologue stage
  int cur = 0;
  for (int t = 0; t < NT; ++t) {
    if (t + 1 < NT) stage(cur ^ 1, t + 1);   // issue next-tile loads FIRST
    compute(cur);                             // compute covers the loads
    __syncthreads();                          // vmcnt(0) drain + barrier
    cur ^= 1;
  }

  // ---- coalesced epilogue via LDS bounce ----
  if (EPI == 0 || EPI == 1) {
    u16* C = shm;                       // [BM][128] bf16
#pragma unroll
    for (int nn = 0; nn < 4; ++nn) {
      int ccol = wc * 64 + nn * 16 + rofs;
      float bv = bias[n0 + ccol];
#pragma unroll
      for (int mm = 0; mm < AMM; ++mm)
#pragma unroll
        for (int r = 0; r < 4; ++r) {
          int crow = wr * HALF + mm * 16 + q4 * 4 + r;
          float v = acc[mm][nn][r] + bv;
          if (EPI == 1) v = 0.5f * v * (1.f + erff(v * 0.70710678118f));
          C[crow * 128 + ccol] = f2bf(v);
        }
    }
    __syncthreads();
    for (int c = tid; c < BM * 16; c += 256) {    // BM rows x 16 chunks of 16B
      int row = c >> 4, off = (c & 15) * 8;
      *(short8*)(outb + (size_t)(m0 + row) * N + n0 + off) = *(const short8*)&C[row * 128 + off];
    }
  } else {
    float* Cf = (float*)shm;            // [HALF][128] fp32, two row-passes
#pragma unroll
    for (int p = 0; p < 2; ++p) {
      if (wr == p) {
#pragma unroll
        for (int nn = 0; nn < 4; ++nn) {
          int ccol = wc * 64 + nn * 16 + rofs;
          float bv = bias[n0 + ccol];
#pragma unroll
          for (int mm = 0; mm < AMM; ++mm)
#pragma unroll
            for (int r = 0; r < 4; ++r)
              Cf[(mm * 16 + q4 * 4 + r) * 128 + ccol] = acc[mm][nn][r] + bv;
        }
      }
      __syncthreads();
      for (int c = tid; c < HALF * 32; c += 256) {  // HALF rows x 32 float4
        int row = c >> 5, off = (c & 31) * 4;
        size_t idx = (size_t)(m0 + p * HALF + row) * N + n0 + off;
        float4 rv = *(const float4*)(res + idx);
        float4 cv = *(const float4*)&Cf[row * 128 + off];
        cv.x += rv.x; cv.y += rv.y; cv.z += rv.z; cv.w += rv.w;
        *(float4*)(outf + idx) = cv;
      }
      __syncthreads();
    }
  }
}

// ---------------- RoPE + QKV split (+V transpose) ----------------
// Q is pre-scaled by 0.125 * log2(e) so attention scores land in log2 domain.
__global__ __launch_bounds__(256) void rope_split(
    const u16* __restrict__ qkv, const int* __restrict__ pos,
    u16* __restrict__ Q, u16* __restrict__ Kk, u16* __restrict__ Vt)
{
  int st = blockIdx.x, bh = blockIdx.y;
  int b = bh >> 4, hh = bh & 15;
  int s0 = st * 64;
  int tid = threadIdx.x;
  __shared__ u16 vtile[64][72];

  for (int i = tid; i < 64 * 32; i += 256) {
    int sl = i >> 5, dp = i & 31;
    int s = s0 + sl;
    float p = (float)pos[b * SEQ + s];
    float freq = exp2f((float)dp * -0.4152410118609203f); // 10000^(-dp/32)
    float ang = p * freq;
    float sn, c;
    __sincosf(ang, &sn, &c);
    const u16* qr = qkv + (size_t)(b * SEQ + s) * 3072 + hh * 64;
    float q1 = bf2f(qr[dp]),        q2 = bf2f(qr[dp + 32]);
    float k1 = bf2f(qr[1024 + dp]), k2 = bf2f(qr[1024 + dp + 32]);
    size_t ob = ((size_t)bh * SEQ + s) * HD;
    const float QS = 0.18033688011112042f; // 0.125 * log2(e)
    Q[ob + dp]       = f2bf((q1 * c - q2 * sn) * QS);
    Q[ob + dp + 32]  = f2bf((q2 * c + q1 * sn) * QS);
    Kk[ob + dp]      = f2bf(k1 * c - k2 * sn);
    Kk[ob + dp + 32] = f2bf(k2 * c + k1 * sn);
  }
  for (int i = tid; i < 64 * 64; i += 256) {
    int sl = i >> 6, d = i & 63;
    vtile[d][sl] = qkv[(size_t)(b * SEQ + s0 + sl) * 3072 + 2048 + hh * 64 + d];
  }
  __syncthreads();
  for (int i = tid; i < 64 * 64; i += 256) {
    int d = i >> 6, sl = i & 63;
    Vt[((size_t)bh * HD + d) * SEQ + s0 + sl] = vtile[d][sl];
  }
}

// ---------------- flash attention: 64 q-rows/block, KV tiles of 64, 2-phase dbuf ----------------
// No-max softmax (bounded-score argument); row-sum via ones-MFMA;
// coalesced O-write via LDS bounce.
__global__ __launch_bounds__(256) void attn_kernel(
    const u16* __restrict__ Q, const u16* __restrict__ K,
    const u16* __restrict__ Vt, u16* __restrict__ O)
{
  __shared__ u16 Ks[2][64 * 64];
  __shared__ u16 Vs[2][64 * 64];
  __shared__ u16 Ps[4 * 16 * 64];
  int qt = blockIdx.x, bh = blockIdx.y;
  int b = bh >> 4, hh = bh & 15;
  const u16* Qp = Q + ((size_t)bh * SEQ + qt * 64) * HD;
  const u16* Kp = K + (size_t)bh * SEQ * HD;
  const u16* Vp = Vt + (size_t)bh * HD * SEQ;
  int tid = threadIdx.x, lane = tid & 63, w = tid >> 6;
  int rofs = lane & 15, q4 = lane >> 4;
  int kofs = q4 * 8;

  short8 aq0 = *(const short8*)&Qp[(w * 16 + rofs) * HD + kofs];
  short8 aq1 = *(const short8*)&Qp[(w * 16 + rofs) * HD + 32 + kofs];

  short8 ones;
#pragma unroll
  for (int j = 0; j < 8; ++j) ones[j] = (short)0x3F80; // bf16 1.0

  f32x4 o[4] = {};
  f32x4 lsum = {};

  int srow = tid >> 3;
  int sg0 = ((tid & 7) ^ (srow & 7)) * 8; // swizzled source chunk (elements)
  u16* pw = &Ps[w * 16 * 64];

#define A_STAGE(BUF, T0) do { \
    gl_lds16(Kp + (size_t)((T0) + srow) * HD + sg0, &Ks[BUF][tid * 8]); \
    gl_lds16(Kp + (size_t)((T0) + 32 + srow) * HD + sg0, &Ks[BUF][tid * 8 + 2048]); \
    gl_lds16(Vp + (size_t)srow * SEQ + (T0) + sg0, &Vs[BUF][tid * 8]); \
    gl_lds16(Vp + (size_t)(32 + srow) * SEQ + (T0) + sg0, &Vs[BUF][tid * 8 + 2048]); \
  } while (0)

  auto tile = [&](const u16* KsB, const u16* VsB) {
    f32x4 s[4] = {};
#pragma unroll
    for (int n = 0; n < 4; ++n) {
      int krow = n * 16 + rofs;
      short8 bk0 = *lds_row128(KsB, krow, q4);
      short8 bk1 = *lds_row128(KsB, krow, 4 + q4);
      s[n] = __builtin_amdgcn_mfma_f32_16x16x32_bf16(aq0, bk0, s[n], 0, 0, 0);
      s[n] = __builtin_amdgcn_mfma_f32_16x16x32_bf16(aq1, bk1, s[n], 0, 0, 0);
    }
#pragma unroll
    for (int n = 0; n < 4; ++n)
#pragma unroll
      for (int r = 0; r < 4; ++r) {
        int prow = q4 * 4 + r;
        int pbyte = (n * 16 + rofs) * 2;
        float p = __builtin_amdgcn_exp2f(s[n][r]);
        *(u16*)((char*)pw + prow * 128 + (pbyte ^ ((prow & 7) << 4))) = f2bf(p);
      }
    short8 pa0 = *lds_row128(pw, rofs, q4);
    short8 pa1 = *lds_row128(pw, rofs, 4 + q4);
    lsum = __builtin_amdgcn_mfma_f32_16x16x32_bf16(pa0, ones, lsum, 0, 0, 0);
    lsum = __builtin_amdgcn_mfma_f32_16x16x32_bf16(pa1, ones, lsum, 0, 0, 0);
#pragma unroll
    for (int n = 0; n < 4; ++n) {
      int vrow = n * 16 + rofs;
      short8 bv0 = *lds_row128(VsB, vrow, q4);
      short8 bv1 = *lds_row128(VsB, vrow, 4 + q4);
      o[n] = __builtin_amdgcn_mfma_f32_16x16x32_bf16(pa0, bv0, o[n], 0, 0, 0);
      o[n] = __builtin_amdgcn_mfma_f32_16x16x32_bf16(pa1, bv1, o[n], 0, 0, 0);
    }
  };

  A_STAGE(0, 0);
  __syncthreads();
  for (int t0 = 0; t0 < SEQ; t0 += 128) {
    if (t0 + 64 < SEQ) A_STAGE(1, t0 + 64);
    tile(Ks[0], Vs[0]);
    __syncthreads();
    if (t0 + 128 < SEQ) A_STAGE(0, t0 + 128);
    tile(Ks[1], Vs[1]);
    __syncthreads();
  }
#undef A_STAGE

#pragma unroll
  for (int r = 0; r < 4; ++r) {
    float inv = 1.f / lsum[r];
    int lrow = w * 16 + q4 * 4 + r;
#pragma unroll
    for (int n = 0; n < 4; ++n)
      Ps[lrow * 64 + n * 16 + rofs] = f2bf(o[n][r] * inv);
  }
  __syncthreads();
  for (int c = tid; c < 512; c += 256) {     // 64 rows x 8 chunks of 16B
    int row = c >> 3, off = (c & 7) * 8;
    int sq = qt * 64 + row;
    *(short8*)(O + ((size_t)b * SEQ + sq) * DIMC + hh * 64 + off) = *(const short8*)&Ps[row * 64 + off];
  }
}

extern "C" void kernel_launch(void* const* d_in, const int* in_sizes, int n_in,
                              void* d_out, int out_size, void* d_ws, size_t ws_size,
                              hipStream_t stream) {
  const float* x     = (const float*)d_in[0];
  const int*   pos   = (const int*)  d_in[1];
  const float* ln1_w = (const float*)d_in[2];
  const float* ln1_b = (const float*)d_in[3];
  const float* qkv_w = (const float*)d_in[4];
  const float* qkv_b = (const float*)d_in[5];
  const float* o_w   = (const float*)d_in[6];
  const float* o_b   = (const float*)d_in[7];
  const float* ln2_w = (const float*)d_in[8];
  const float* ln2_b = (const float*)d_in[9];
  const float* w1    = (const float*)d_in[10];
  const float* b1    = (const float*)d_in[11];
  const float* w2    = (const float*)d_in[12];
  const float* b2    = (const float*)d_in[13];
  float* out = (float*)d_out;

  // workspace layout (bytes) — total 92,274,688 (88 MB), carefully aliased
  char* ws = (char*)d_ws;
  u16* WqkvT = (u16*)(ws + 0);          // 3072x1024 bf16 (6 MB)
  u16* WoT   = (u16*)(ws + 6291456);    // 1024x1024 (2 MB)
  u16* W1T   = (u16*)(ws + 8388608);    // 4096x1024 (8 MB)
  u16* W2T   = (u16*)(ws + 16777216);   // 1024x4096 (8 MB)
  u16* xn    = (u16*)(ws + 25165824);   // 4096x1024 (8 MB)
  u16* qkvbf = (u16*)(ws + 33554432);   // 4096x3072 (24 MB)
  u16* Qb    = (u16*)(ws + 58720256);   // 8 MB
  u16* Kb    = (u16*)(ws + 67108864);   // 8 MB
  u16* Vtb   = (u16*)(ws + 75497472);   // 8 MB
  u16* attnb = (u16*)(ws + 83886080);   // 8 MB
  u16* hbuf  = (u16*)(ws + 25165824);   // 4096x4096 (32 MB) — aliases xn+qkvbf (dead)
  float* x2  = (float*)(ws + 58720256); // 16 MB — aliases Qb+Kb (dead after attn)
  u16* xn2   = (u16*)(ws + 75497472);   // 8 MB — aliases Vtb (dead after attn)

  transpose_cast<<<dim3(3072/32, 1024/32), dim3(32, 8), 0, stream>>>(qkv_w, WqkvT, 1024, 3072);
  transpose_cast<<<dim3(1024/32, 1024/32), dim3(32, 8), 0, stream>>>(o_w,  WoT,  1024, 1024);
  transpose_cast<<<dim3(4096/32, 1024/32), dim3(32, 8), 0, stream>>>(w1,   W1T,  1024, 4096);
  transpose_cast<<<dim3(1024/32, 4096/32), dim3(32, 8), 0, stream>>>(w2,   W2T,  4096, 1024);

  ln_kernel<<<TOK, 256, 0, stream>>>(x, ln1_w, ln1_b, xn);
  // grid: (N-tiles, M-tiles); all grids satisfy nwg%8==0, gx%4==0, gy%4==0
  gemm_bt<0,128><<<dim3(24, 32), 256, 0, stream>>>(xn, WqkvT, qkv_b, nullptr, qkvbf, nullptr, 4096, 3072, 1024);
  rope_split<<<dim3(32, 32), 256, 0, stream>>>(qkvbf, pos, Qb, Kb, Vtb);
  attn_kernel<<<dim3(32, 32), 256, 0, stream>>>(Qb, Kb, Vtb, attnb);
  gemm_bt<2,64><<<dim3(8, 64), 256, 0, stream>>>(attnb, WoT, o_b, x, nullptr, x2, 4096, 1024, 1024);
  ln_kernel<<<TOK, 256, 0, stream>>>(x2, ln2_w, ln2_b, xn2);
  gemm_bt<1,128><<<dim3(32, 32), 256, 0, stream>>>(xn2, W1T, b1, nullptr, hbuf, nullptr, 4096, 4096, 1024);
  gemm_bt<2,64><<<dim3(8, 64), 256, 0, stream>>>(hbuf, W2T, b2, x2, nullptr, out, 4096, 1024, 4096);
}